// Round 9
// baseline (10347.421 us; speedup 1.0000x reference)
//
#include <hip/hip_runtime.h>
#include <hip/hip_fp16.h>

// Problem constants
#define TT 2048
#define II 1739
#define HN 256
#define H3 768
#define L2E 1.44269504088896f

typedef _Float16 h8 __attribute__((ext_vector_type(8)));
typedef _Float16 h2 __attribute__((ext_vector_type(2)));
typedef float f4 __attribute__((ext_vector_type(4)));

__device__ __forceinline__ float fast_exp2(float x) {
#if defined(__has_builtin)
#if __has_builtin(__builtin_amdgcn_exp2f)
  return __builtin_amdgcn_exp2f(x);
#else
  return exp2f(x);
#endif
#else
  return exp2f(x);
#endif
}

__device__ __forceinline__ float fast_rcp(float x) {
#if defined(__has_builtin)
#if __has_builtin(__builtin_amdgcn_rcpf)
  return __builtin_amdgcn_rcpf(x);
#else
  return 1.f / x;
#endif
#else
  return 1.f / x;
#endif
}

// C[M,N] = ((A[M,K] @ B[N,K]^T) + bias1[n] + (n < b2lim ? bias2[n] : 0)) * (n < slim ? s_lo : s_hi)
// 64x64 tile, 256 threads, 4x4 micro-tile per thread.
__global__ __launch_bounds__(256) void gemm_abt(
    const float* __restrict__ A, int M, int K,
    const float* __restrict__ B, int N,
    const float* __restrict__ bias1, const float* __restrict__ bias2, int b2lim,
    float s_lo, float s_hi, int slim,
    float* __restrict__ C) {
  __shared__ float As[16][64];
  __shared__ float Bs[16][64];
  const int tid = threadIdx.x;
  const int m0 = blockIdx.y * 64, n0 = blockIdx.x * 64;
  const int lr = tid >> 2;        // 0..63  (row within tile for loads)
  const int lk = (tid & 3) * 4;   // 0,4,8,12
  const int cx = tid & 15, cy = tid >> 4;
  float acc[4][4] = {};

  for (int k0 = 0; k0 < K; k0 += 16) {
#pragma unroll
    for (int i = 0; i < 4; ++i) {
      int k = k0 + lk + i;
      As[lk + i][lr] = (k < K) ? A[(size_t)(m0 + lr) * K + k] : 0.f;
      int bn = n0 + lr;
      Bs[lk + i][lr] = (k < K && bn < N) ? B[(size_t)bn * K + k] : 0.f;
    }
    __syncthreads();
#pragma unroll
    for (int k = 0; k < 16; ++k) {
      float4 av = *(const float4*)&As[k][cy * 4];
      float4 bv = *(const float4*)&Bs[k][cx * 4];
      const float aa[4] = {av.x, av.y, av.z, av.w};
      const float bb[4] = {bv.x, bv.y, bv.z, bv.w};
#pragma unroll
      for (int i = 0; i < 4; ++i)
#pragma unroll
        for (int j = 0; j < 4; ++j) acc[i][j] = fmaf(aa[i], bb[j], acc[i][j]);
    }
    __syncthreads();
  }
#pragma unroll
  for (int i = 0; i < 4; ++i) {
    int m = m0 + cy * 4 + i;
#pragma unroll
    for (int j = 0; j < 4; ++j) {
      int n = n0 + cx * 4 + j;
      if (n < N) {
        float b = bias1 ? bias1[n] : 0.f;
        if (bias2 && n < b2lim) b += bias2[n];
        float s = (n < slim) ? s_lo : s_hi;
        C[(size_t)m * N + n] = (acc[i][j] + b) * s;
      }
    }
  }
}

// Sequential GRU scan on a single CU (1 block, 512 threads = 8 waves,
// 2 waves/EU pinned -> 256-reg/wave budget).
//
// Established rounds 0-8: weights = 75% of the CU register file; a VALU
// (dot2) datapath cannot fit its working set beside them -> constant ~2x
// issue inflation. MFMA reads AGPR operands for free; r5 proved the
// fragment layouts (refcheck-passed) but spilled ~20 regs. This round =
// r5's datapath with the working set squeezed under 256:
//  - B-frag liveness capped at 2 via explicit 1-deep rotation +
//    sched_barrier(0) per k-cluster (r5 likely kept all 8 live = +24).
//  - NO gsc redistribution: with B = h replicated across all 16 cols,
//    every lane's D regs already hold units 32w + kg*4 + j (+16 for the
//    second fragment) -> gates computed straight from acc (redundant
//    over cols; writers = col 0). Saves regs AND a serial phase.
//  - x / bhn / fp32-h_old live in LDS, not registers (~35 regs saved):
//    x double-buffered, staged one step ahead by waves 0-2 (loads issued
//    at step top, ds_write after the MFMA wall; latency hidden under it).
//    h_old kept in fp32 LDS -> r4's exact update numerics.
//
// Fragment conventions (verified by r5's passing refcheck):
//   A-frag (16x16x32 f16): lane holds row = lane&15, k = (lane>>4)*8+j.
//   B = h replicated: lane value = h[kk*32 + (lane>>4)*8 + j] (one
//     broadcast ds_read_b128 per k-cluster).
//   D: col = lane&15 (all identical), row = (lane>>4)*4 + reg.
// Wave w owns units [32w, 32w+32): frag pair (g, hf) covers rows
// g*256 + 32w + hf*16 + [0,16). 6 frags x 8 k-clusters = 48 MFMA/step.
__global__ __attribute__((amdgpu_flat_work_group_size(512, 512)))
__attribute__((amdgpu_waves_per_eu(2, 2))) void gru_seq(
    const float* __restrict__ xp,      // [T, 768], pre-scaled by L2E/2L2E
    const float* __restrict__ Whh,     // [768, 256]
    const float* __restrict__ bhh,     // [768]
    const float* __restrict__ h0,      // [256] or nullptr (zeros)
    float* __restrict__ hs_out,        // [T, 256] or nullptr
    float* __restrict__ hT_out) {      // [256] or nullptr
  __shared__ _Float16 h16[2][HN];   // matvec B-source (f16 h, dbuf)
  __shared__ float    h32[2][HN];   // fp32 h_old (dbuf)
  __shared__ float    xb[2][H3];    // x-projection staging (dbuf)
  __shared__ float    bl[HN];       // bhn pre-scaled

  const int tid = threadIdx.x;
  const int lane = tid & 63;
  const int wv = tid >> 6;        // 0..7
  const int col = lane & 15;
  const int kg = lane >> 4;       // 0..3
  const int uA = wv * 32 + kg * 4;  // half-A units uA..uA+3; half-B: +16

  // Stationary weight fragments (192 regs; AGPR-eligible, MFMA-only).
  h8 a[6][8];
#pragma unroll
  for (int g = 0; g < 3; ++g)
#pragma unroll
    for (int hf = 0; hf < 2; ++hf) {
      const float sc = (g == 2) ? (2.f * L2E) : L2E;
      const int row = g * HN + wv * 32 + hf * 16 + col;
      const float* wr = Whh + (size_t)row * HN + kg * 8;
#pragma unroll
      for (int kk = 0; kk < 8; ++kk) {
        float4 f0 = *(const float4*)(wr + kk * 32);
        float4 f1 = *(const float4*)(wr + kk * 32 + 4);
        h8 v;
        v[0] = (_Float16)(f0.x * sc); v[1] = (_Float16)(f0.y * sc);
        v[2] = (_Float16)(f0.z * sc); v[3] = (_Float16)(f0.w * sc);
        v[4] = (_Float16)(f1.x * sc); v[5] = (_Float16)(f1.y * sc);
        v[6] = (_Float16)(f1.z * sc); v[7] = (_Float16)(f1.w * sc);
        a[g * 2 + hf][kk] = v;
      }
    }

  if (tid < HN) {
    float hv = h0 ? h0[tid] : 0.f;
    h16[0][tid] = (_Float16)hv;
    h32[0][tid] = hv;
    bl[tid] = bhh[2 * HN + tid] * (2.f * L2E);
  }
  if (wv < 3) {  // stage x for t = 0
    float4 v = *(const float4*)(xp + wv * 256 + lane * 4);
    *(float4*)&xb[0][wv * 256 + lane * 4] = v;
  }
  __syncthreads();

  for (int t = 0; t < TT; ++t) {
    const int cur = t & 1;
    const int nxt = cur ^ 1;

    // Issue next step's x loads (latency hides under the MFMA wall;
    // t+1 over-read at t=2047 lands in the adjacent workspace buffer).
    float4 xnv;
    if (wv < 3)
      xnv = *(const float4*)(xp + (size_t)(t + 1) * H3 + wv * 256 + lane * 4);

    // Matvec: 48 MFMAs; B-frag rotation 1-deep, sched_barrier-fenced.
    const _Float16* hc = &h16[cur][0];
    f4 acc0, acc1, acc2, acc3, acc4, acc5;
    h8 b0 = *(const h8*)&hc[kg * 8];
    {
      const f4 z4 = {0.f, 0.f, 0.f, 0.f};
      h8 bn = *(const h8*)&hc[32 + kg * 8];
      acc0 = __builtin_amdgcn_mfma_f32_16x16x32_f16(a[0][0], b0, z4, 0, 0, 0);
      acc1 = __builtin_amdgcn_mfma_f32_16x16x32_f16(a[1][0], b0, z4, 0, 0, 0);
      acc2 = __builtin_amdgcn_mfma_f32_16x16x32_f16(a[2][0], b0, z4, 0, 0, 0);
      acc3 = __builtin_amdgcn_mfma_f32_16x16x32_f16(a[3][0], b0, z4, 0, 0, 0);
      acc4 = __builtin_amdgcn_mfma_f32_16x16x32_f16(a[4][0], b0, z4, 0, 0, 0);
      acc5 = __builtin_amdgcn_mfma_f32_16x16x32_f16(a[5][0], b0, z4, 0, 0, 0);
      __builtin_amdgcn_sched_barrier(0);
      b0 = bn;
    }
#pragma unroll
    for (int kk = 1; kk < 8; ++kk) {
      h8 bn;
      if (kk < 7) bn = *(const h8*)&hc[(kk + 1) * 32 + kg * 8];
      acc0 = __builtin_amdgcn_mfma_f32_16x16x32_f16(a[0][kk], b0, acc0, 0, 0, 0);
      acc1 = __builtin_amdgcn_mfma_f32_16x16x32_f16(a[1][kk], b0, acc1, 0, 0, 0);
      acc2 = __builtin_amdgcn_mfma_f32_16x16x32_f16(a[2][kk], b0, acc2, 0, 0, 0);
      acc3 = __builtin_amdgcn_mfma_f32_16x16x32_f16(a[3][kk], b0, acc3, 0, 0, 0);
      acc4 = __builtin_amdgcn_mfma_f32_16x16x32_f16(a[4][kk], b0, acc4, 0, 0, 0);
      acc5 = __builtin_amdgcn_mfma_f32_16x16x32_f16(a[5][kk], b0, acc5, 0, 0, 0);
      if (kk < 7) {
        __builtin_amdgcn_sched_barrier(0);
        b0 = bn;
      }
    }

    // Write the staged x for t+1 (load issued ~a full MFMA wall ago).
    if (wv < 3) *(float4*)&xb[nxt][wv * 256 + lane * 4] = xnv;

    // Gates half A: units uA..uA+3 from acc0/acc2/acc4 (r, z, n).
    {
      f4 xr = *(const f4*)&xb[cur][uA];
      f4 xz = *(const f4*)&xb[cur][HN + uA];
      f4 xn = *(const f4*)&xb[cur][2 * HN + uA];
      f4 bh = *(const f4*)&bl[uA];
      f4 ho = *(const f4*)&h32[cur][uA];
      f4 hnew;
#pragma unroll
      for (int j = 0; j < 4; ++j) {
        float r = fast_rcp(1.f + fast_exp2(-(xr[j] + acc0[j])));
        float z = fast_rcp(1.f + fast_exp2(-(xz[j] + acc2[j])));
        float n = fmaf(2.f, fast_rcp(1.f + fast_exp2(-fmaf(r, acc4[j] + bh[j], xn[j]))), -1.f);
        hnew[j] = fmaf(z, ho[j] - n, n);
      }
      if (col == 0) {
        *(f4*)&h32[nxt][uA] = hnew;
        h2 p0 = {(_Float16)hnew[0], (_Float16)hnew[1]};
        h2 p1 = {(_Float16)hnew[2], (_Float16)hnew[3]};
        uint2 pw = {__builtin_bit_cast(uint, p0), __builtin_bit_cast(uint, p1)};
        *(uint2*)&h16[nxt][uA] = pw;
        if (hs_out) *(f4*)&hs_out[(size_t)t * HN + uA] = hnew;
        if (hT_out && t == TT - 1) *(f4*)&hT_out[uA] = hnew;
      }
    }
    __builtin_amdgcn_sched_barrier(0);
    // Gates half B: units uA+16..uA+19 from acc1/acc3/acc5.
    {
      const int uB = uA + 16;
      f4 xr = *(const f4*)&xb[cur][uB];
      f4 xz = *(const f4*)&xb[cur][HN + uB];
      f4 xn = *(const f4*)&xb[cur][2 * HN + uB];
      f4 bh = *(const f4*)&bl[uB];
      f4 ho = *(const f4*)&h32[cur][uB];
      f4 hnew;
#pragma unroll
      for (int j = 0; j < 4; ++j) {
        float r = fast_rcp(1.f + fast_exp2(-(xr[j] + acc1[j])));
        float z = fast_rcp(1.f + fast_exp2(-(xz[j] + acc3[j])));
        float n = fmaf(2.f, fast_rcp(1.f + fast_exp2(-fmaf(r, acc5[j] + bh[j], xn[j]))), -1.f);
        hnew[j] = fmaf(z, ho[j] - n, n);
      }
      if (col == 0) {
        *(f4*)&h32[nxt][uB] = hnew;
        h2 p0 = {(_Float16)hnew[0], (_Float16)hnew[1]};
        h2 p1 = {(_Float16)hnew[2], (_Float16)hnew[3]};
        uint2 pw = {__builtin_bit_cast(uint, p0), __builtin_bit_cast(uint, p1)};
        *(uint2*)&h16[nxt][uB] = pw;
        if (hs_out) *(f4*)&hs_out[(size_t)t * HN + uB] = hnew;
        if (hT_out && t == TT - 1) *(f4*)&hT_out[uB] = hnew;
      }
    }
    __syncthreads();
  }
}

extern "C" void kernel_launch(void* const* d_in, const int* in_sizes, int n_in,
                              void* d_out, int out_size, void* d_ws, size_t ws_size,
                              hipStream_t stream) {
  const float* x     = (const float*)d_in[0];   // [1, 2048, 1739]
  const float* Wih_e = (const float*)d_in[2];   // [768, 1739]
  const float* Whh_e = (const float*)d_in[3];   // [768, 256]
  const float* bih_e = (const float*)d_in[4];   // [768]
  const float* bhh_e = (const float*)d_in[5];   // [768]
  const float* Wih_d = (const float*)d_in[6];
  const float* Whh_d = (const float*)d_in[7];
  const float* bih_d = (const float*)d_in[8];
  const float* bhh_d = (const float*)d_in[9];
  const float* Wout  = (const float*)d_in[10];  // [1739, 256]
  const float* bout  = (const float*)d_in[11];  // [1739]
  float* out = (float*)d_out;                   // [2048, 1, 1739]

  float* ws = (float*)d_ws;
  float* xpe  = ws;                              // 2048*768
  float* xpd  = xpe + (size_t)TT * H3;           // 2048*768  (xpe over-read pad)
  float* hs   = xpd + (size_t)TT * H3;           // 2048*256  (xpd over-read pad)
  float* henc = hs + (size_t)TT * HN;            // 256

  dim3 blk(256);
  // x-projections, pre-scaled for exp2-based gates:
  //   rows [0,512) (r,z): (x@W^T + bih + bhh) * log2e
  //   rows [512,768) (n): (x@W^T + bih) * 2log2e   (bhh n-part in-gate)
  gemm_abt<<<dim3(12, 32), blk, 0, stream>>>(x, TT, II, Wih_e, H3, bih_e, bhh_e, 2 * HN,
                                             L2E, 2.f * L2E, 2 * HN, xpe);
  gemm_abt<<<dim3(12, 32), blk, 0, stream>>>(x, TT, II, Wih_d, H3, bih_d, bhh_d, 2 * HN,
                                             L2E, 2.f * L2E, 2 * HN, xpd);
  // encoder scan -> henc
  gru_seq<<<1, 512, 0, stream>>>(xpe, Whh_e, bhh_e, nullptr, nullptr, henc);
  // decoder scan -> hs
  gru_seq<<<1, 512, 0, stream>>>(xpd, Whh_d, bhh_d, henc, hs, nullptr);
  // output projection (unscaled)
  gemm_abt<<<dim3(28, 32), blk, 0, stream>>>(hs, TT, HN, Wout, II, bout, nullptr, 0,
                                             1.f, 1.f, 0, out);
}

// Round 10
// 5733.212 us; speedup vs baseline: 1.8048x; 1.8048x over previous
//
#include <hip/hip_runtime.h>
#include <hip/hip_fp16.h>

// Problem constants
#define TT 2048
#define II 1739
#define HN 256
#define H3 768
#define L2E 1.44269504088896f

typedef _Float16 h2 __attribute__((ext_vector_type(2)));

__device__ __forceinline__ float fdot2(h2 a, h2 b, float c) {
#if defined(__has_builtin)
#if __has_builtin(__builtin_amdgcn_fdot2)
  return __builtin_amdgcn_fdot2(a, b, c, false);
#else
  return fmaf((float)a[0], (float)b[0], fmaf((float)a[1], (float)b[1], c));
#endif
#else
  return fmaf((float)a[0], (float)b[0], fmaf((float)a[1], (float)b[1], c));
#endif
}

__device__ __forceinline__ float fast_exp2(float x) {
#if defined(__has_builtin)
#if __has_builtin(__builtin_amdgcn_exp2f)
  return __builtin_amdgcn_exp2f(x);
#else
  return exp2f(x);
#endif
#else
  return exp2f(x);
#endif
}

__device__ __forceinline__ float fast_rcp(float x) {
#if defined(__has_builtin)
#if __has_builtin(__builtin_amdgcn_rcpf)
  return __builtin_amdgcn_rcpf(x);
#else
  return 1.f / x;
#endif
#else
  return 1.f / x;
#endif
}

template <int CTRL>
__device__ __forceinline__ float dpp_qperm(float v) {
  int r = __builtin_amdgcn_update_dpp(0, __builtin_bit_cast(int, v), CTRL, 0xF, 0xF, true);
  return __builtin_bit_cast(float, r);
}

// ---------------------------------------------------------------------------
// Shared 64x64 GEMM tile body. C[M,N] = ((A[M,K] @ B[N,K]^T) + bias1[n]
// + (n<b2lim ? bias2[n]:0)) * (n<slim ? s_lo:s_hi). 256 logical threads
// (callers with 512 threads pass tid = threadIdx.x & 255: duplicate lanes
// redo identical work -- benign WAW on LDS/global with identical values).
// ---------------------------------------------------------------------------
__device__ __forceinline__ void gemm_tile(
    int tid, int bx, int by,
    const float* __restrict__ A, int M, int K,
    const float* __restrict__ B, int N,
    const float* __restrict__ bias1, const float* __restrict__ bias2, int b2lim,
    float s_lo, float s_hi, int slim,
    float* __restrict__ C,
    float (*As)[64], float (*Bs)[64]) {
  const int m0 = by * 64, n0 = bx * 64;
  const int lr = tid >> 2;        // 0..63
  const int lk = (tid & 3) * 4;   // 0,4,8,12
  const int cx = tid & 15, cy = tid >> 4;
  float acc[4][4] = {};

  for (int k0 = 0; k0 < K; k0 += 16) {
#pragma unroll
    for (int i = 0; i < 4; ++i) {
      int k = k0 + lk + i;
      As[lk + i][lr] = (k < K) ? A[(size_t)(m0 + lr) * K + k] : 0.f;
      int bn = n0 + lr;
      Bs[lk + i][lr] = (k < K && bn < N) ? B[(size_t)bn * K + k] : 0.f;
    }
    __syncthreads();
#pragma unroll
    for (int k = 0; k < 16; ++k) {
      float4 av = *(const float4*)&As[k][cy * 4];
      float4 bv = *(const float4*)&Bs[k][cx * 4];
      const float aa[4] = {av.x, av.y, av.z, av.w};
      const float bb[4] = {bv.x, bv.y, bv.z, bv.w};
#pragma unroll
      for (int i = 0; i < 4; ++i)
#pragma unroll
        for (int j = 0; j < 4; ++j) acc[i][j] = fmaf(aa[i], bb[j], acc[i][j]);
    }
    __syncthreads();
  }
#pragma unroll
  for (int i = 0; i < 4; ++i) {
    int m = m0 + cy * 4 + i;
#pragma unroll
    for (int j = 0; j < 4; ++j) {
      int n = n0 + cx * 4 + j;
      if (n < N) {
        float b = bias1 ? bias1[n] : 0.f;
        if (bias2 && n < b2lim) b += bias2[n];
        float s = (n < slim) ? s_lo : s_hi;
        C[(size_t)m * N + n] = (acc[i][j] + b) * s;
      }
    }
  }
}

// Standalone 256-thread GEMM (used for the xpe projection, g1).
__global__ __launch_bounds__(256) void gemm_abt(
    const float* __restrict__ A, int M, int K,
    const float* __restrict__ B, int N,
    const float* __restrict__ bias1, const float* __restrict__ bias2, int b2lim,
    float s_lo, float s_hi, int slim,
    float* __restrict__ C) {
  __shared__ float As[16][64];
  __shared__ float Bs[16][64];
  gemm_tile(threadIdx.x, blockIdx.x, blockIdx.y, A, M, K, B, N,
            bias1, bias2, b2lim, s_lo, s_hi, slim, C, As, Bs);
}

// ---------------------------------------------------------------------------
// Sequential GRU scan (exact round-4 body -- best verified: 2141 us/scan).
// 512 threads; quad q owns units {2q, 2q+1} for all three gates; one
// __syncthreads per step; double-buffered f16 h at chunk-stride 40;
// exp2-form gates with pre-scaled args. New: optional `prog` -- after the
// end-of-step barrier (which drains vmcnt -> hs stores are in this XCD's
// L2), thread 0 publishes a device-scope RELEASE flag per 64-step tile
// (flushes L2 -> hs visible to consumer blocks on other XCDs).
// ---------------------------------------------------------------------------
__device__ void gru_scan(
    const float* __restrict__ xp,      // [T, 768], pre-scaled by L2E/2L2E
    const float* __restrict__ Whh,     // [768, 256]
    const float* __restrict__ bhh,     // [768]
    const float* __restrict__ h0,      // [256] or nullptr (zeros)
    float* __restrict__ hs_out,        // [T, 256] or nullptr
    float* __restrict__ hT_out,        // [256] or nullptr
    unsigned int* __restrict__ prog) { // [32] tile flags or nullptr
  __shared__ __align__(16) uint hbufd[2][160];

  const int tid = threadIdx.x;
  const int lane = tid & 63;
  const int wv = tid >> 6;              // 0..7
  const int kc = lane & 3;              // k-chunk [64*kc, 64*kc+64)
  const int q = wv * 16 + (lane >> 2);  // 0..127; units 2q, 2q+1
  const int u0 = 2 * q;

  // wreg[uu*3+gg]: unit u0+uu, gate gg (0=r,1=z,2=n), pre-scaled.
  h2 wreg[6][32];
#pragma unroll
  for (int uu = 0; uu < 2; ++uu) {
#pragma unroll
    for (int gg = 0; gg < 3; ++gg) {
      const float sc = (gg == 2) ? (2.f * L2E) : L2E;
      const float* wr = Whh + (size_t)(u0 + uu + gg * HN) * HN + kc * 64;
#pragma unroll
      for (int p = 0; p < 32; ++p) {
        float2 f = *(const float2*)(wr + 2 * p);
        wreg[uu * 3 + gg][p] = h2{(_Float16)(f.x * sc), (_Float16)(f.y * sc)};
      }
    }
  }

  float hj0 = h0 ? h0[u0] : 0.f;
  float hj1 = h0 ? h0[u0 + 1] : 0.f;
  const float bhn0 = bhh[2 * HN + u0] * (2.f * L2E);
  const float bhn1 = bhh[2 * HN + u0 + 1] * (2.f * L2E);

  if (tid < 128) {
    float a = h0 ? h0[2 * tid] : 0.f;
    float b = h0 ? h0[2 * tid + 1] : 0.f;
    h2 pv = h2{(_Float16)a, (_Float16)b};
    hbufd[0][(tid >> 5) * 40 + (tid & 31)] = __builtin_bit_cast(uint, pv);
  }
  __syncthreads();

  const int wadr = (q >> 5) * 40 + (q & 31);

  for (int t = 0; t < TT; ++t) {
    // This step's x-projection (issued early; lands during the matvec).
    float2 xr, xz, xn;
    {
      const float* xpt = xp + (size_t)t * H3 + u0;
      xr = *(const float2*)(xpt);
      xz = *(const float2*)(xpt + HN);
      xn = *(const float2*)(xpt + 2 * HN);
    }

    // Matvec: 6 rows x 64 k per thread (f16 dot2, fp32 accumulate).
    const uint* hb = &hbufd[t & 1][kc * 40];
    float a[6] = {0.f, 0.f, 0.f, 0.f, 0.f, 0.f};
#pragma unroll
    for (int qq = 0; qq < 8; ++qq) {
      uint4 v = *(const uint4*)&hb[qq * 4];
      uint hwv[4] = {v.x, v.y, v.z, v.w};
#pragma unroll
      for (int i = 0; i < 6; ++i)
#pragma unroll
        for (int p = 0; p < 4; ++p)
          a[i] = fdot2(wreg[i][qq * 4 + p], __builtin_bit_cast(h2, hwv[p]), a[i]);
    }

    // Quad butterfly: all 4 lanes end with the full k-sum (bit-identical).
#pragma unroll
    for (int i = 0; i < 6; ++i) {
      float v = a[i];
      v += dpp_qperm<0xB1>(v);  // xor 1
      v += dpp_qperm<0x4E>(v);  // xor 2
      a[i] = v;
    }

    // Gates, fully local (args pre-scaled by log2e / 2log2e).
    float r0 = fast_rcp(1.f + fast_exp2(-(xr.x + a[0])));
    float z0 = fast_rcp(1.f + fast_exp2(-(xz.x + a[1])));
    float n0 = fmaf(2.f, fast_rcp(1.f + fast_exp2(-fmaf(r0, a[2] + bhn0, xn.x))), -1.f);
    hj0 = fmaf(z0, hj0 - n0, n0);
    float r1 = fast_rcp(1.f + fast_exp2(-(xr.y + a[3])));
    float z1 = fast_rcp(1.f + fast_exp2(-(xz.y + a[4])));
    float n1 = fmaf(2.f, fast_rcp(1.f + fast_exp2(-fmaf(r1, a[5] + bhn1, xn.y))), -1.f);
    hj1 = fmaf(z1, hj1 - n1, n1);

    h2 pv = h2{(_Float16)hj0, (_Float16)hj1};
    if (kc == 0) {
      hbufd[(t & 1) ^ 1][wadr] = __builtin_bit_cast(uint, pv);
      if (hs_out) *(float2*)&hs_out[(size_t)t * HN + u0] = make_float2(hj0, hj1);
    }
    __syncthreads();
    // Publish tile readiness (decoder only). The barrier above drained
    // vmcnt for every wave -> all hs stores of tile t>>6 are in this
    // XCD's L2; the agent-scope release store writes them back.
    if (prog && (t & 63) == 63 && tid == 0) {
      __hip_atomic_store(&prog[t >> 6], 1u, __ATOMIC_RELEASE,
                         __HIP_MEMORY_SCOPE_AGENT);
    }
  }
  if (hT_out && kc == 0) *(float2*)&hT_out[u0] = make_float2(hj0, hj1);
}

// ---------------------------------------------------------------------------
// F1: encoder scan (block 0) + xpd projection GEMM (blocks 1..384).
// No inter-block communication: GEMM blocks free-run on idle CUs while the
// scan runs -> deadlock-impossible under any dispatch order.
// ---------------------------------------------------------------------------
__global__ __launch_bounds__(512) void fused_enc(
    const float* __restrict__ xpe, const float* __restrict__ Whh_e,
    const float* __restrict__ bhh_e, float* __restrict__ henc,
    const float* __restrict__ x, const float* __restrict__ Wih_d,
    const float* __restrict__ bih_d, const float* __restrict__ bhh_d,
    float* __restrict__ xpd) {
  if (blockIdx.x == 0) {
    gru_scan(xpe, Whh_e, bhh_e, nullptr, nullptr, henc, nullptr);
  } else {
    __shared__ float As[16][64];
    __shared__ float Bs[16][64];
    const int b = blockIdx.x - 1;          // 0..383
    gemm_tile(threadIdx.x & 255, b % 12, b / 12, x, TT, II, Wih_d, H3,
              bih_d, bhh_d, 2 * HN, L2E, 2.f * L2E, 2 * HN, xpd, As, Bs);
  }
}

// ---------------------------------------------------------------------------
// F2: decoder scan (block 0) + output projection (blocks 1..200 = persistent
// workers). Workers pull 64x64 out-tiles (896 jobs, m-tile-major) from an
// atomic queue and acquire-spin on the scan's per-m-tile flag. 201 blocks at
// 1 block/CU (kernel-wide VGPR = scan's 128V+128A) are all co-resident by
// capacity -> no dispatch-order deadlock (G16-safe).
// ---------------------------------------------------------------------------
#define NJOBS (28 * 32)
__global__ __launch_bounds__(512) void fused_dec(
    const float* __restrict__ xpd, const float* __restrict__ Whh_d,
    const float* __restrict__ bhh_d, const float* __restrict__ henc,
    float* __restrict__ hs, unsigned int* __restrict__ prog,
    int* __restrict__ jobctr,
    const float* __restrict__ Wout, const float* __restrict__ bout,
    float* __restrict__ out) {
  if (blockIdx.x == 0) {
    gru_scan(xpd, Whh_d, bhh_d, henc, hs, nullptr, prog);
  } else {
    __shared__ float As[16][64];
    __shared__ float Bs[16][64];
    __shared__ int sjob;
    const int tid = threadIdx.x;
    for (;;) {
      if (tid == 0) sjob = atomicAdd(jobctr, 1);
      __syncthreads();
      const int job = sjob;
      __syncthreads();  // sjob consumed before next overwrite
      if (job >= NJOBS) break;
      const int by = job / 28, bx = job % 28;  // m-tile-major: readiness order
      if (tid == 0) {
        while (__hip_atomic_load(&prog[by], __ATOMIC_ACQUIRE,
                                 __HIP_MEMORY_SCOPE_AGENT) == 0u)
          __builtin_amdgcn_s_sleep(8);
      }
      __syncthreads();
      gemm_tile(tid & 255, bx, by, hs, TT, HN, Wout, II, bout, nullptr, 0,
                1.f, 1.f, 0, out, As, Bs);
    }
  }
}

extern "C" void kernel_launch(void* const* d_in, const int* in_sizes, int n_in,
                              void* d_out, int out_size, void* d_ws, size_t ws_size,
                              hipStream_t stream) {
  const float* x     = (const float*)d_in[0];   // [1, 2048, 1739]
  const float* Wih_e = (const float*)d_in[2];   // [768, 1739]
  const float* Whh_e = (const float*)d_in[3];   // [768, 256]
  const float* bih_e = (const float*)d_in[4];   // [768]
  const float* bhh_e = (const float*)d_in[5];   // [768]
  const float* Wih_d = (const float*)d_in[6];
  const float* Whh_d = (const float*)d_in[7];
  const float* bih_d = (const float*)d_in[8];
  const float* bhh_d = (const float*)d_in[9];
  const float* Wout  = (const float*)d_in[10];  // [1739, 256]
  const float* bout  = (const float*)d_in[11];  // [1739]
  float* out = (float*)d_out;                   // [2048, 1, 1739]

  float* ws = (float*)d_ws;
  float* xpe  = ws;                              // 2048*768
  float* xpd  = xpe + (size_t)TT * H3;           // 2048*768
  float* hs   = xpd + (size_t)TT * H3;           // 2048*256
  float* henc = hs + (size_t)TT * HN;            // 256
  unsigned int* prog = (unsigned int*)(henc + HN);  // 32 tile flags
  int* jobctr = (int*)(prog + 32);                  // 1 counter

  // Zero the flags + job counter (async memset is graph-capture safe).
  hipMemsetAsync(prog, 0, 64 * sizeof(unsigned int), stream);

  dim3 blk(256);
  // g1: xpe projection, pre-scaled for exp2-based gates:
  //   rows [0,512) (r,z): (x@W^T + bih + bhh) * log2e
  //   rows [512,768) (n): (x@W^T + bih) * 2log2e   (bhh n-part in-gate)
  gemm_abt<<<dim3(12, 32), blk, 0, stream>>>(x, TT, II, Wih_e, H3, bih_e, bhh_e, 2 * HN,
                                             L2E, 2.f * L2E, 2 * HN, xpe);
  // F1: encoder scan (block 0) || xpd projection (blocks 1..384).
  fused_enc<<<dim3(385), dim3(512), 0, stream>>>(xpe, Whh_e, bhh_e, henc,
                                                 x, Wih_d, bih_d, bhh_d, xpd);
  // F2: decoder scan (block 0) || output projection workers (blocks 1..200).
  fused_dec<<<dim3(201), dim3(512), 0, stream>>>(xpd, Whh_d, bhh_d, henc,
                                                 hs, prog, jobctr,
                                                 Wout, bout, out);
}

// Round 11
// 4597.582 us; speedup vs baseline: 2.2506x; 1.2470x over previous
//
#include <hip/hip_runtime.h>
#include <hip/hip_fp16.h>

// Problem constants
#define TT 2048
#define II 1739
#define IIP 1760              // II zero-padded to a multiple of 32 (f16 GEMM K)
#define HN 256
#define H3 768
#define L2E 1.44269504088896f

typedef _Float16 h2 __attribute__((ext_vector_type(2)));
typedef _Float16 h8 __attribute__((ext_vector_type(8)));
typedef float f4 __attribute__((ext_vector_type(4)));

__device__ __forceinline__ float fdot2(h2 a, h2 b, float c) {
#if defined(__has_builtin)
#if __has_builtin(__builtin_amdgcn_fdot2)
  return __builtin_amdgcn_fdot2(a, b, c, false);
#else
  return fmaf((float)a[0], (float)b[0], fmaf((float)a[1], (float)b[1], c));
#endif
#else
  return fmaf((float)a[0], (float)b[0], fmaf((float)a[1], (float)b[1], c));
#endif
}

__device__ __forceinline__ float fast_exp2(float x) {
#if defined(__has_builtin)
#if __has_builtin(__builtin_amdgcn_exp2f)
  return __builtin_amdgcn_exp2f(x);
#else
  return exp2f(x);
#endif
#else
  return exp2f(x);
#endif
}

__device__ __forceinline__ float fast_rcp(float x) {
#if defined(__has_builtin)
#if __has_builtin(__builtin_amdgcn_rcpf)
  return __builtin_amdgcn_rcpf(x);
#else
  return 1.f / x;
#endif
#else
  return 1.f / x;
#endif
}

template <int CTRL>
__device__ __forceinline__ float dpp_qperm(float v) {
  int r = __builtin_amdgcn_update_dpp(0, __builtin_bit_cast(int, v), CTRL, 0xF, 0xF, true);
  return __builtin_bit_cast(float, r);
}

__device__ __forceinline__ h8 h8zero() {
  h8 v;
#pragma unroll
  for (int j = 0; j < 8; ++j) v[j] = (_Float16)0.f;
  return v;
}

// ---------------------------------------------------------------------------
// One-time f32 -> f16 weight conversion (zero-padded K for the W_ih's).
//   We/Wd [768][1739] -> weh/wdh [768][1760] (pad = 0)
//   Wo    [1739][256] -> woh     [1739][256]
// ---------------------------------------------------------------------------
#define WSEG (768 * IIP)
#define OSEG (II * HN)
__global__ __launch_bounds__(256) void prep_f16(
    const float* __restrict__ We, const float* __restrict__ Wd,
    const float* __restrict__ Wo,
    _Float16* __restrict__ weh, _Float16* __restrict__ wdh,
    _Float16* __restrict__ woh) {
  const int total = 2 * WSEG + OSEG;
  for (int i = blockIdx.x * 256 + threadIdx.x; i < total; i += gridDim.x * 256) {
    if (i < WSEG) {
      int r = i / IIP, k = i - r * IIP;
      weh[i] = (k < II) ? (_Float16)We[(size_t)r * II + k] : (_Float16)0.f;
    } else if (i < 2 * WSEG) {
      int j = i - WSEG;
      int r = j / IIP, k = j - r * IIP;
      wdh[j] = (k < II) ? (_Float16)Wd[(size_t)r * II + k] : (_Float16)0.f;
    } else {
      int j = i - 2 * WSEG;
      woh[j] = (_Float16)Wo[j];
    }
  }
}

// ---------------------------------------------------------------------------
// MFMA f16 GEMM: C[M,N] = ((A[.,K]_f32 @ B16[N,Kp]_f16^T) + bias1[n]
//   + (n<b2lim ? bias2[n]:0)) * (n<slim ? s_lo : s_hi)
// Block = 256 thr = 4 waves; tile 64(M) x 64(N); k-step 32; fp32 accum.
// A rows may be only 4B-aligned (K=1739 odd) -> memcpy loads; staged to f16
// in LDS. B16 is pre-converted, zero-padded to Kp (multiple of 32).
// Fragment conventions (validated by r5/r9 passing refchecks):
//   A operand: lane&15 -> m-row, (lane>>4)*8+j -> k.
//   B operand: lane&15 -> n-col, (lane>>4)*8+j -> k.
//   D: col = lane&15 (n), row = (lane>>4)*4 + reg (m).
// LDS tiles [64][40] f16: row stride 80 B -> b128 accesses spread 16-lane
// groups over all 32 banks (<=2-way aliasing = free).
// ---------------------------------------------------------------------------
__global__ __launch_bounds__(256) void gemm16(
    const float* __restrict__ A, int K,
    const _Float16* __restrict__ B16, int N, int Kp,
    const float* __restrict__ bias1, const float* __restrict__ bias2, int b2lim,
    float s_lo, float s_hi, int slim,
    float* __restrict__ C) {
  __shared__ _Float16 As[64][40];
  __shared__ _Float16 Bs[64][40];
  const int tid = threadIdx.x;
  const int w = tid >> 6, lane = tid & 63;
  const int col = lane & 15, kg = lane >> 4;
  const int m0 = blockIdx.y * 64, n0 = blockIdx.x * 64;
  const int srow = tid >> 2, skq = tid & 3;   // staging: row 0..63, k-oct 0..3
  f4 acc[4];
#pragma unroll
  for (int m = 0; m < 4; ++m) acc[m] = f4{0.f, 0.f, 0.f, 0.f};

  for (int k0 = 0; k0 < Kp; k0 += 32) {
    const int kk = k0 + skq * 8;
    // A: row m0+srow, k = kk..kk+7 (f32, possibly 4B-aligned, guarded tail).
    h8 av = h8zero(), bv = h8zero();
    {
      const float* ap = A + (size_t)(m0 + srow) * K + kk;
      if (kk + 8 <= K) {
        float4 f0, f1;
        __builtin_memcpy(&f0, ap, 16);
        __builtin_memcpy(&f1, ap + 4, 16);
        av[0] = (_Float16)f0.x; av[1] = (_Float16)f0.y;
        av[2] = (_Float16)f0.z; av[3] = (_Float16)f0.w;
        av[4] = (_Float16)f1.x; av[5] = (_Float16)f1.y;
        av[6] = (_Float16)f1.z; av[7] = (_Float16)f1.w;
      } else if (kk < K) {
#pragma unroll
        for (int j = 0; j < 8; ++j)
          if (kk + j < K) av[j] = (_Float16)ap[j];
      }
    }
    {
      const int bn = n0 + srow;
      if (bn < N) bv = *(const h8*)(B16 + (size_t)bn * Kp + kk);
    }
    __syncthreads();  // prior iteration's frag reads done before overwrite
    *(h8*)&As[srow][skq * 8] = av;
    *(h8*)&Bs[srow][skq * 8] = bv;
    __syncthreads();
    h8 b = *(const h8*)&Bs[w * 16 + col][kg * 8];
#pragma unroll
    for (int m = 0; m < 4; ++m) {
      h8 a = *(const h8*)&As[m * 16 + col][kg * 8];
      acc[m] = __builtin_amdgcn_mfma_f32_16x16x32_f16(a, b, acc[m], 0, 0, 0);
    }
  }

  const int n = n0 + w * 16 + col;
  if (n < N) {
    float bb = bias1[n];
    if (bias2 && n < b2lim) bb += bias2[n];
    const float s = (n < slim) ? s_lo : s_hi;
#pragma unroll
    for (int m = 0; m < 4; ++m) {
      const int mr = m0 + m * 16 + kg * 4;
#pragma unroll
      for (int r = 0; r < 4; ++r)
        C[(size_t)(mr + r) * N + n] = (acc[m][r] + bb) * s;
    }
  }
}

// ---------------------------------------------------------------------------
// Sequential GRU scan -- EXACT round-4 body (best verified: 2140 us/scan).
// 512 threads; quad q owns units {2q, 2q+1} for all three gates; one
// __syncthreads per step; double-buffered f16 h at chunk-stride 40;
// exp2-form gates with pre-scaled args.
// ---------------------------------------------------------------------------
__global__ __launch_bounds__(512) void gru_seq(
    const float* __restrict__ xp,      // [T, 768], pre-scaled by L2E/2L2E
    const float* __restrict__ Whh,     // [768, 256]
    const float* __restrict__ bhh,     // [768]
    const float* __restrict__ h0,      // [256] or nullptr (zeros)
    float* __restrict__ hs_out,        // [T, 256] or nullptr
    float* __restrict__ hT_out) {      // [256] or nullptr
  __shared__ __align__(16) uint hbufd[2][160];

  const int tid = threadIdx.x;
  const int lane = tid & 63;
  const int wv = tid >> 6;              // 0..7
  const int kc = lane & 3;              // k-chunk [64*kc, 64*kc+64)
  const int q = wv * 16 + (lane >> 2);  // 0..127; units 2q, 2q+1
  const int u0 = 2 * q;

  // wreg[uu*3+gg]: unit u0+uu, gate gg (0=r,1=z,2=n), pre-scaled.
  h2 wreg[6][32];
#pragma unroll
  for (int uu = 0; uu < 2; ++uu) {
#pragma unroll
    for (int gg = 0; gg < 3; ++gg) {
      const float sc = (gg == 2) ? (2.f * L2E) : L2E;
      const float* wr = Whh + (size_t)(u0 + uu + gg * HN) * HN + kc * 64;
#pragma unroll
      for (int p = 0; p < 32; ++p) {
        float2 f = *(const float2*)(wr + 2 * p);
        wreg[uu * 3 + gg][p] = h2{(_Float16)(f.x * sc), (_Float16)(f.y * sc)};
      }
    }
  }

  float hj0 = h0 ? h0[u0] : 0.f;
  float hj1 = h0 ? h0[u0 + 1] : 0.f;
  const float bhn0 = bhh[2 * HN + u0] * (2.f * L2E);
  const float bhn1 = bhh[2 * HN + u0 + 1] * (2.f * L2E);

  if (tid < 128) {
    float a = h0 ? h0[2 * tid] : 0.f;
    float b = h0 ? h0[2 * tid + 1] : 0.f;
    h2 pv = h2{(_Float16)a, (_Float16)b};
    hbufd[0][(tid >> 5) * 40 + (tid & 31)] = __builtin_bit_cast(uint, pv);
  }
  __syncthreads();

  const int wadr = (q >> 5) * 40 + (q & 31);

  for (int t = 0; t < TT; ++t) {
    // This step's x-projection (issued early; lands during the matvec).
    float2 xr, xz, xn;
    {
      const float* xpt = xp + (size_t)t * H3 + u0;
      xr = *(const float2*)(xpt);
      xz = *(const float2*)(xpt + HN);
      xn = *(const float2*)(xpt + 2 * HN);
    }

    // Matvec: 6 rows x 64 k per thread (f16 dot2, fp32 accumulate).
    const uint* hb = &hbufd[t & 1][kc * 40];
    float a[6] = {0.f, 0.f, 0.f, 0.f, 0.f, 0.f};
#pragma unroll
    for (int qq = 0; qq < 8; ++qq) {
      uint4 v = *(const uint4*)&hb[qq * 4];
      uint hwv[4] = {v.x, v.y, v.z, v.w};
#pragma unroll
      for (int i = 0; i < 6; ++i)
#pragma unroll
        for (int p = 0; p < 4; ++p)
          a[i] = fdot2(wreg[i][qq * 4 + p], __builtin_bit_cast(h2, hwv[p]), a[i]);
    }

    // Quad butterfly: all 4 lanes end with the full k-sum (bit-identical).
#pragma unroll
    for (int i = 0; i < 6; ++i) {
      float v = a[i];
      v += dpp_qperm<0xB1>(v);  // xor 1
      v += dpp_qperm<0x4E>(v);  // xor 2
      a[i] = v;
    }

    // Gates, fully local (args pre-scaled by log2e / 2log2e).
    float r0 = fast_rcp(1.f + fast_exp2(-(xr.x + a[0])));
    float z0 = fast_rcp(1.f + fast_exp2(-(xz.x + a[1])));
    float n0 = fmaf(2.f, fast_rcp(1.f + fast_exp2(-fmaf(r0, a[2] + bhn0, xn.x))), -1.f);
    hj0 = fmaf(z0, hj0 - n0, n0);
    float r1 = fast_rcp(1.f + fast_exp2(-(xr.y + a[3])));
    float z1 = fast_rcp(1.f + fast_exp2(-(xz.y + a[4])));
    float n1 = fmaf(2.f, fast_rcp(1.f + fast_exp2(-fmaf(r1, a[5] + bhn1, xn.y))), -1.f);
    hj1 = fmaf(z1, hj1 - n1, n1);

    h2 pv = h2{(_Float16)hj0, (_Float16)hj1};
    if (kc == 0) {
      hbufd[(t & 1) ^ 1][wadr] = __builtin_bit_cast(uint, pv);
      if (hs_out) *(float2*)&hs_out[(size_t)t * HN + u0] = make_float2(hj0, hj1);
    }
    __syncthreads();
  }
  if (hT_out && kc == 0) *(float2*)&hT_out[u0] = make_float2(hj0, hj1);
}

extern "C" void kernel_launch(void* const* d_in, const int* in_sizes, int n_in,
                              void* d_out, int out_size, void* d_ws, size_t ws_size,
                              hipStream_t stream) {
  const float* x     = (const float*)d_in[0];   // [1, 2048, 1739]
  const float* Wih_e = (const float*)d_in[2];   // [768, 1739]
  const float* Whh_e = (const float*)d_in[3];   // [768, 256]
  const float* bih_e = (const float*)d_in[4];   // [768]
  const float* bhh_e = (const float*)d_in[5];   // [768]
  const float* Wih_d = (const float*)d_in[6];
  const float* Whh_d = (const float*)d_in[7];
  const float* bih_d = (const float*)d_in[8];
  const float* bhh_d = (const float*)d_in[9];
  const float* Wout  = (const float*)d_in[10];  // [1739, 256]
  const float* bout  = (const float*)d_in[11];  // [1739]
  float* out = (float*)d_out;                   // [2048, 1, 1739]

  // Workspace layout (floats; all segment starts 16B-aligned):
  float* ws = (float*)d_ws;
  float* xpe  = ws;                              // 2048*768
  float* xpd  = xpe + (size_t)TT * H3;           // 2048*768
  float* hs   = xpd + (size_t)TT * H3;           // 2048*256 (fp32, g3 input)
  float* henc = hs + (size_t)TT * HN;            // 256
  _Float16* weh = (_Float16*)(henc + HN);        // [768][1760] f16
  _Float16* wdh = weh + (size_t)768 * IIP;       // [768][1760] f16
  _Float16* woh = wdh + (size_t)768 * IIP;       // [1739][256] f16
  // total ~21.0 MB

  // One-time weight conversion to f16 (zero-padded K for the W_ih's).
  prep_f16<<<dim3(1024), dim3(256), 0, stream>>>(Wih_e, Wih_d, Wout,
                                                 weh, wdh, woh);
  // x-projections via MFMA f16, pre-scaled for exp2-based gates:
  //   rows [0,512) (r,z): (x@W^T + bih + bhh) * log2e
  //   rows [512,768) (n): (x@W^T + bih) * 2log2e   (bhh n-part in-gate)
  gemm16<<<dim3(12, 32), dim3(256), 0, stream>>>(x, II, weh, H3, IIP,
      bih_e, bhh_e, 2 * HN, L2E, 2.f * L2E, 2 * HN, xpe);
  gemm16<<<dim3(12, 32), dim3(256), 0, stream>>>(x, II, wdh, H3, IIP,
      bih_d, bhh_d, 2 * HN, L2E, 2.f * L2E, 2 * HN, xpd);
  // encoder scan -> henc
  gru_seq<<<1, 512, 0, stream>>>(xpe, Whh_e, bhh_e, nullptr, nullptr, henc);
  // decoder scan -> hs
  gru_seq<<<1, 512, 0, stream>>>(xpd, Whh_d, bhh_d, henc, hs, nullptr);
  // output projection via MFMA f16 (unscaled)
  gemm16<<<dim3(28, 32), dim3(256), 0, stream>>>(hs, HN, woh, II, HN,
      bout, nullptr, 0, 1.f, 1.f, 0, out);
}